// Round 1
// baseline (244.525 us; speedup 1.0000x reference)
//
#include <hip/hip_runtime.h>
#include <hip/hip_bf16.h>

// ---- problem constants ----
#define N_GAUSS 4096
#define N_PTS   32768
#define BLOCK   256
#define NSPLIT  8          // gaussian-dim split for occupancy: 128*8 = 1024 blocks
#define GSTRIDE 32         // floats per packed gaussian (128 B, aligned)

// SH constants (folded into coefficients at prep time)
#define SH_C0 0.28209479177387814f
#define SH_C1 0.4886025119029199f

// ---------------------------------------------------------------------------
// Kernel 1: per-gaussian preprocessing.
// Packs, per gaussian (32 floats):
//   [0..2]  xyz center
//   [3]     opacity = sigmoid(logit)
//   [4..9]  symmetric precision matrix pxx,pxy,pxz,pyy,pyz,pzz  (R diag(1/s^2) R^T)
//   [10..25] SH coeffs with the constant (and sign) pre-multiplied
// ---------------------------------------------------------------------------
__global__ __launch_bounds__(256) void prep_kernel(
    const float* __restrict__ xyz, const float* __restrict__ sh_dc,
    const float* __restrict__ sh_rest, const float* __restrict__ scaling,
    const float* __restrict__ rotation, const float* __restrict__ opl,
    float* __restrict__ gp)
{
    int g = blockIdx.x * blockDim.x + threadIdx.x;
    if (g >= N_GAUSS) return;

    // scales -> inverse variances
    float i0 = __expf(-2.0f * scaling[3*g+0]);
    float i1 = __expf(-2.0f * scaling[3*g+1]);
    float i2 = __expf(-2.0f * scaling[3*g+2]);

    // normalized quaternion -> rotation matrix
    float r = rotation[4*g+0], x = rotation[4*g+1];
    float y = rotation[4*g+2], z = rotation[4*g+3];
    float n = rsqrtf(r*r + x*x + y*y + z*z);
    r *= n; x *= n; y *= n; z *= n;
    float R00 = 1.f - 2.f*(y*y + z*z), R01 = 2.f*(x*y - r*z), R02 = 2.f*(x*z + r*y);
    float R10 = 2.f*(x*y + r*z), R11 = 1.f - 2.f*(x*x + z*z), R12 = 2.f*(y*z - r*x);
    float R20 = 2.f*(x*z - r*y), R21 = 2.f*(y*z + r*x), R22 = 1.f - 2.f*(x*x + y*y);

    // prec[i][k] = sum_j R[i][j] * invvar[j] * R[k][j]
    float pxx = R00*R00*i0 + R01*R01*i1 + R02*R02*i2;
    float pxy = R00*R10*i0 + R01*R11*i1 + R02*R12*i2;
    float pxz = R00*R20*i0 + R01*R21*i1 + R02*R22*i2;
    float pyy = R10*R10*i0 + R11*R11*i1 + R12*R12*i2;
    float pyz = R10*R20*i0 + R11*R21*i1 + R12*R22*i2;
    float pzz = R20*R20*i0 + R21*R21*i1 + R22*R22*i2;

    float op = 1.f / (1.f + __expf(-opl[g]));

    float* G = gp + (size_t)g * GSTRIDE;
    G[0] = xyz[3*g+0]; G[1] = xyz[3*g+1]; G[2] = xyz[3*g+2]; G[3] = op;
    G[4] = pxx; G[5] = pxy; G[6] = pxz; G[7] = pyy; G[8] = pyz; G[9] = pzz;

    const float* sr = sh_rest + (size_t)g * 15;
    G[10] =  SH_C0 * sh_dc[g];
    G[11] = -SH_C1 * sr[0];          // * y
    G[12] =  SH_C1 * sr[1];          // * z
    G[13] = -SH_C1 * sr[2];          // * x
    G[14] =  1.0925484305920792f  * sr[3];   // * xy
    G[15] = -1.0925484305920792f  * sr[4];   // * yz
    G[16] =  0.31539156525252005f * sr[5];   // * (3zz-1)
    G[17] = -1.0925484305920792f  * sr[6];   // * xz
    G[18] =  0.5462742152960396f  * sr[7];   // * (xx-yy)
    G[19] = -0.5900435899266435f  * sr[8];   // * y(3xx-yy)
    G[20] =  2.890611442640554f   * sr[9];   // * xy*z
    G[21] = -0.4570457994644658f  * sr[10];  // * y(5zz-1)
    G[22] =  0.3731763325901154f  * sr[11];  // * z(5zz-3)
    G[23] = -0.4570457994644658f  * sr[12];  // * x(5zz-1)
    G[24] =  1.445305721320277f   * sr[13];  // * z(xx-yy)
    G[25] = -0.5900435899266435f  * sr[14];  // * x(xx-yy-3zz)
    G[26] = 0.f; G[27] = 0.f; G[28] = 0.f; G[29] = 0.f; G[30] = 0.f; G[31] = 0.f;
}

// ---------------------------------------------------------------------------
// Kernel 2: main point x gaussian evaluation.
// grid = (N_PTS/BLOCK, NSPLIT). Thread = one point; loops over its gaussian
// segment. Gaussian params are wave-uniform -> scalar loads (s_load), so the
// VALU only does the per-pair math (~60 ops). Wave-uniform skip of the SH
// block when exp underflows for all 64 lanes.
// ---------------------------------------------------------------------------
__global__ __launch_bounds__(BLOCK) void gauss_kernel(
    const float* __restrict__ pts, const float* __restrict__ gp,
    float* __restrict__ out)
{
    int pt  = blockIdx.x * BLOCK + threadIdx.x;
    int seg = blockIdx.y;
    float px = pts[3*pt+0], py = pts[3*pt+1], pz = pts[3*pt+2];

    float opac = 0.f, sig = 0.f;
    const int g0 = seg * (N_GAUSS / NSPLIT);
    const int g1 = g0 + (N_GAUSS / NSPLIT);

    for (int g = g0; g < g1; ++g) {
        const float* __restrict__ G = gp + (size_t)g * GSTRIDE;
        float dx = px - G[0], dy = py - G[1], dz = pz - G[2];
        float pxx = G[4], pxy = G[5], pxz = G[6];
        float pyy = G[7], pyz = G[8], pzz = G[9];

        float vx = pxx*dx + pxy*dy + pxz*dz;
        float vy = pxy*dx + pyy*dy + pyz*dz;
        float vz = pxz*dx + pyz*dy + pzz*dz;
        float maha = dx*vx + dy*vy + dz*vz;
        float w = G[3] * __expf(-0.5f * maha);
        opac += w;

        if (__any(w > 1e-13f)) {
            float d2   = dx*dx + dy*dy + dz*dz;
            float rinv = rsqrtf(d2);
            float x = -dx * rinv, y = -dy * rinv, z = -dz * rinv;
            float xx = x*x, yy = y*y, zz = z*z;
            float xy = x*y, yz = y*z, xz = x*z;

            float res = G[10];
            res += y * G[11];
            res += z * G[12];
            res += x * G[13];
            res += xy * G[14];
            res += yz * G[15];
            res += (3.f*zz - 1.f) * G[16];      // 2zz-xx-yy with xx+yy+zz=1
            res += xz * G[17];
            float xxmyy = xx - yy;
            res += xxmyy * G[18];
            res += y * (3.f*xx - yy) * G[19];
            res += (xy * z) * G[20];
            float f5z1 = 5.f*zz - 1.f;          // 4zz-xx-yy
            res += y * f5z1 * G[21];
            res += z * (5.f*zz - 3.f) * G[22];  // 2zz-3xx-3yy
            res += x * f5z1 * G[23];
            res += z * xxmyy * G[24];
            res += x * (xxmyy - 3.f*zz) * G[25];

            float mag = fmaxf(res, 0.f);
            sig += w * mag;
        }
    }

    atomicAdd(&out[pt], opac);
    atomicAdd(&out[N_PTS + pt], sig);
}

extern "C" void kernel_launch(void* const* d_in, const int* in_sizes, int n_in,
                              void* d_out, int out_size, void* d_ws, size_t ws_size,
                              hipStream_t stream) {
    const float* pts      = (const float*)d_in[0];  // network_pts (32768,3)
    // d_in[1] network_view, d_in[2] network_tx: unused by the reference
    const float* xyz      = (const float*)d_in[3];  // (4096,3)
    const float* sh_dc    = (const float*)d_in[4];  // (4096,1)
    const float* sh_rest  = (const float*)d_in[5];  // (4096,15)
    const float* scaling  = (const float*)d_in[6];  // (4096,3)
    const float* rotation = (const float*)d_in[7];  // (4096,4)
    const float* opl      = (const float*)d_in[8];  // (4096,1)

    float* out = (float*)d_out;                     // [opac(32768) | sig(32768)]
    float* gp  = (float*)d_ws;                      // packed gaussians, 512 KB

    hipMemsetAsync(d_out, 0, (size_t)out_size * sizeof(float), stream);

    prep_kernel<<<dim3((N_GAUSS + 255) / 256), dim3(256), 0, stream>>>(
        xyz, sh_dc, sh_rest, scaling, rotation, opl, gp);

    dim3 grid(N_PTS / BLOCK, NSPLIT);
    gauss_kernel<<<grid, dim3(BLOCK), 0, stream>>>(pts, gp, out);
}

// Round 2
// 208.634 us; speedup vs baseline: 1.1720x; 1.1720x over previous
//
#include <hip/hip_runtime.h>
#include <hip/hip_bf16.h>

// ---- problem constants ----
#define N_GAUSS 4096
#define N_PTS   32768
#define BLOCK   256
#define NSPLIT  16         // gaussian-dim split: 128*16 = 2048 blocks -> 8 blocks/CU
#define GSTRIDE 32         // floats per packed gaussian (128 B, aligned)
#define NCELL   4096       // 16^3 morton cells for point sorting

#define SH_C0 0.28209479177387814f
#define SH_C1 0.4886025119029199f

// Workspace layout (floats):
//   gp      : [0, 131072)              packed gaussians, 512 KB
//   hist    : [131072, 135168) as int  cell histogram -> exclusive offsets
//   cursor  : [135168, 139264) as int  scatter cursors
//   cellid  : [139264, 172032) as int  per-point cell id
//   perm    : [172032, 204800) as int  sorted point order
#define WS_GP     0
#define WS_HIST   131072
#define WS_CURSOR 135168
#define WS_CELLID 139264
#define WS_PERM   172032

// ---------------------------------------------------------------------------
// Kernel 1: per-gaussian preprocessing.
//   [0..2]  xyz center, [3] cull threshold T_g (skip pair if d2 > T_g)
//   [4..9]  0.5 * precision matrix (so maha' = d^T P' d, w = exp(lnop - maha'))
//   [10]    ln(opacity)
//   [12..27] SH coeffs with constants pre-multiplied
// ---------------------------------------------------------------------------
__global__ __launch_bounds__(256) void prep_kernel(
    const float* __restrict__ xyz, const float* __restrict__ sh_dc,
    const float* __restrict__ sh_rest, const float* __restrict__ scaling,
    const float* __restrict__ rotation, const float* __restrict__ opl,
    float* __restrict__ gp)
{
    int g = blockIdx.x * blockDim.x + threadIdx.x;
    if (g >= N_GAUSS) return;

    float s0 = scaling[3*g+0], s1 = scaling[3*g+1], s2 = scaling[3*g+2];
    float i0 = __expf(-2.0f * s0);   // inverse variances
    float i1 = __expf(-2.0f * s1);
    float i2 = __expf(-2.0f * s2);
    float maxs2 = __expf(2.0f * fmaxf(s0, fmaxf(s1, s2)));  // max eigenvalue of covariance

    float r = rotation[4*g+0], x = rotation[4*g+1];
    float y = rotation[4*g+2], z = rotation[4*g+3];
    float n = rsqrtf(r*r + x*x + y*y + z*z);
    r *= n; x *= n; y *= n; z *= n;
    float R00 = 1.f - 2.f*(y*y + z*z), R01 = 2.f*(x*y - r*z), R02 = 2.f*(x*z + r*y);
    float R10 = 2.f*(x*y + r*z), R11 = 1.f - 2.f*(x*x + z*z), R12 = 2.f*(y*z - r*x);
    float R20 = 2.f*(x*z - r*y), R21 = 2.f*(y*z + r*x), R22 = 1.f - 2.f*(x*x + y*y);

    // P' = 0.5 * R diag(invvar) R^T
    float pxx = 0.5f*(R00*R00*i0 + R01*R01*i1 + R02*R02*i2);
    float pxy = 0.5f*(R00*R10*i0 + R01*R11*i1 + R02*R12*i2);
    float pxz = 0.5f*(R00*R20*i0 + R01*R21*i1 + R02*R22*i2);
    float pyy = 0.5f*(R10*R10*i0 + R11*R11*i1 + R12*R12*i2);
    float pyz = 0.5f*(R10*R20*i0 + R11*R21*i1 + R12*R22*i2);
    float pzz = 0.5f*(R20*R20*i0 + R21*R21*i1 + R22*R22*i2);

    float op   = 1.f / (1.f + __expf(-opl[g]));
    float lnop = __logf(op);
    // skip pair iff w = exp(lnop - maha') < 1e-13.
    // maha' >= (0.5/maxs2)*d2, so d2 > 2*maxs2*(lnop+30) => w < e^-30*op < 1e-13
    float Tg = 2.0f * maxs2 * (lnop + 30.0f);

    float* G = gp + (size_t)g * GSTRIDE;
    G[0] = xyz[3*g+0]; G[1] = xyz[3*g+1]; G[2] = xyz[3*g+2]; G[3] = Tg;
    G[4] = pxx; G[5] = pxy; G[6] = pxz; G[7] = pyy; G[8] = pyz; G[9] = pzz;
    G[10] = lnop; G[11] = 0.f;

    const float* sr = sh_rest + (size_t)g * 15;
    G[12] =  SH_C0 * sh_dc[g];
    G[13] = -SH_C1 * sr[0];          // * y
    G[14] =  SH_C1 * sr[1];          // * z
    G[15] = -SH_C1 * sr[2];          // * x
    G[16] =  1.0925484305920792f  * sr[3];   // * xy
    G[17] = -1.0925484305920792f  * sr[4];   // * yz
    G[18] =  0.31539156525252005f * sr[5];   // * (3zz-1)
    G[19] = -1.0925484305920792f  * sr[6];   // * xz
    G[20] =  0.5462742152960396f  * sr[7];   // * (xx-yy)
    G[21] = -0.5900435899266435f  * sr[8];   // * y(3xx-yy)
    G[22] =  2.890611442640554f   * sr[9];   // * xy*z
    G[23] = -0.4570457994644658f  * sr[10];  // * y(5zz-1)
    G[24] =  0.3731763325901154f  * sr[11];  // * z(5zz-3)
    G[25] = -0.4570457994644658f  * sr[12];  // * x(5zz-1)
    G[26] =  1.445305721320277f   * sr[13];  // * z(xx-yy)
    G[27] = -0.5900435899266435f  * sr[14];  // * x(xx-yy-3zz)
    G[28] = 0.f; G[29] = 0.f; G[30] = 0.f; G[31] = 0.f;
}

// ---------------------------------------------------------------------------
// Point spatial sort: 16^3 morton cells over [-3.2, 3.2]^3, counting sort.
// ---------------------------------------------------------------------------
__device__ __forceinline__ int expand4(int b) {
    return (b & 1) | ((b & 2) << 2) | ((b & 4) << 4) | ((b & 8) << 6);
}

__global__ __launch_bounds__(256) void bin_kernel(
    const float* __restrict__ pts, int* __restrict__ hist, int* __restrict__ cellid)
{
    int p = blockIdx.x * blockDim.x + threadIdx.x;
    float x = pts[3*p+0], y = pts[3*p+1], z = pts[3*p+2];
    int cx = min(15, max(0, (int)((x + 3.2f) * 2.5f)));
    int cy = min(15, max(0, (int)((y + 3.2f) * 2.5f)));
    int cz = min(15, max(0, (int)((z + 3.2f) * 2.5f)));
    int cell = expand4(cx) | (expand4(cy) << 1) | (expand4(cz) << 2);
    cellid[p] = cell;
    atomicAdd(&hist[cell], 1);
}

// single-block exclusive scan over 4096 counts (1024 threads x 4 cells each)
__global__ __launch_bounds__(1024) void scan_kernel(
    int* __restrict__ hist, int* __restrict__ cursor)
{
    __shared__ int lds[1024];
    int t = threadIdx.x;
    int b = t * 4;
    int c0 = hist[b], c1 = hist[b+1], c2 = hist[b+2], c3 = hist[b+3];
    int s = c0 + c1 + c2 + c3;
    lds[t] = s;
    __syncthreads();
    for (int off = 1; off < 1024; off <<= 1) {
        int v = (t >= off) ? lds[t - off] : 0;
        __syncthreads();
        lds[t] += v;
        __syncthreads();
    }
    int excl = lds[t] - s;
    int o0 = excl, o1 = o0 + c0, o2 = o1 + c1, o3 = o2 + c2;
    hist[b] = o0; hist[b+1] = o1; hist[b+2] = o2; hist[b+3] = o3;
    cursor[b] = o0; cursor[b+1] = o1; cursor[b+2] = o2; cursor[b+3] = o3;
}

__global__ __launch_bounds__(256) void scatter_kernel(
    const int* __restrict__ cellid, int* __restrict__ cursor, int* __restrict__ perm)
{
    int p = blockIdx.x * blockDim.x + threadIdx.x;
    int pos = atomicAdd(&cursor[cellid[p]], 1);
    perm[pos] = p;
}

// ---------------------------------------------------------------------------
// Main kernel: sorted points -> spatially coherent waves -> wave-level cull.
// ---------------------------------------------------------------------------
__global__ __launch_bounds__(BLOCK) void gauss_kernel(
    const float* __restrict__ pts, const float* __restrict__ gp,
    const int* __restrict__ perm, float* __restrict__ out)
{
    int gid = blockIdx.x * BLOCK + threadIdx.x;
    int pt  = perm[gid];
    int seg = blockIdx.y;
    float px = pts[3*pt+0], py = pts[3*pt+1], pz = pts[3*pt+2];

    float opac = 0.f, sig = 0.f;
    const int g0 = seg * (N_GAUSS / NSPLIT);
    const int g1 = g0 + (N_GAUSS / NSPLIT);

    for (int g = g0; g < g1; ++g) {
        const float* __restrict__ G = gp + (size_t)g * GSTRIDE;
        float dx = px - G[0], dy = py - G[1], dz = pz - G[2];
        float d2 = dx*dx + dy*dy + dz*dz;
        if (__all(d2 > G[3])) continue;   // provably w < 1e-13 on every lane

        float vx = G[4]*dx + G[5]*dy + G[6]*dz;
        float vy = G[5]*dx + G[7]*dy + G[8]*dz;
        float vz = G[6]*dx + G[8]*dy + G[9]*dz;
        float maha = dx*vx + dy*vy + dz*vz;     // already includes the 0.5
        float w = __expf(G[10] - maha);         // op * exp(-0.5 maha)
        opac += w;

        if (__any(w > 1e-13f)) {
            float rinv = rsqrtf(d2);
            float x = -dx * rinv, y = -dy * rinv, z = -dz * rinv;
            float xx = x*x, yy = y*y, zz = z*z;
            float xy = x*y, yz = y*z, xz = x*z;

            float res = G[12];
            res += y * G[13];
            res += z * G[14];
            res += x * G[15];
            res += xy * G[16];
            res += yz * G[17];
            res += (3.f*zz - 1.f) * G[18];
            res += xz * G[19];
            float xxmyy = xx - yy;
            res += xxmyy * G[20];
            res += y * (3.f*xx - yy) * G[21];
            res += (xy * z) * G[22];
            float f5z1 = 5.f*zz - 1.f;
            res += y * f5z1 * G[23];
            res += z * (5.f*zz - 3.f) * G[24];
            res += x * f5z1 * G[25];
            res += z * xxmyy * G[26];
            res += x * (xxmyy - 3.f*zz) * G[27];

            sig += w * fmaxf(res, 0.f);
        }
    }

    atomicAdd(&out[pt], opac);
    atomicAdd(&out[N_PTS + pt], sig);
}

extern "C" void kernel_launch(void* const* d_in, const int* in_sizes, int n_in,
                              void* d_out, int out_size, void* d_ws, size_t ws_size,
                              hipStream_t stream) {
    const float* pts      = (const float*)d_in[0];  // network_pts (32768,3)
    const float* xyz      = (const float*)d_in[3];
    const float* sh_dc    = (const float*)d_in[4];
    const float* sh_rest  = (const float*)d_in[5];
    const float* scaling  = (const float*)d_in[6];
    const float* rotation = (const float*)d_in[7];
    const float* opl      = (const float*)d_in[8];

    float* out    = (float*)d_out;
    float* wsf    = (float*)d_ws;
    float* gp     = wsf + WS_GP;
    int*   hist   = (int*)(wsf + WS_HIST);
    int*   cursor = (int*)(wsf + WS_CURSOR);
    int*   cellid = (int*)(wsf + WS_CELLID);
    int*   perm   = (int*)(wsf + WS_PERM);

    hipMemsetAsync(d_out, 0, (size_t)out_size * sizeof(float), stream);
    hipMemsetAsync(hist, 0, NCELL * sizeof(int), stream);

    prep_kernel<<<dim3((N_GAUSS + 255) / 256), dim3(256), 0, stream>>>(
        xyz, sh_dc, sh_rest, scaling, rotation, opl, gp);
    bin_kernel<<<dim3(N_PTS / 256), dim3(256), 0, stream>>>(pts, hist, cellid);
    scan_kernel<<<dim3(1), dim3(1024), 0, stream>>>(hist, cursor);
    scatter_kernel<<<dim3(N_PTS / 256), dim3(256), 0, stream>>>(cellid, cursor, perm);

    dim3 grid(N_PTS / BLOCK, NSPLIT);
    gauss_kernel<<<grid, dim3(BLOCK), 0, stream>>>(pts, gp, perm, out);
}

// Round 3
// 202.872 us; speedup vs baseline: 1.2053x; 1.0284x over previous
//
#include <hip/hip_runtime.h>
#include <hip/hip_bf16.h>

// ---- problem constants ----
#define N_GAUSS 4096
#define N_PTS   32768
#define BLOCK   256
#define NSPLIT  16         // 128*16 = 2048 blocks -> 8 blocks/CU, 32 waves/CU
#define GSTRIDE 28         // floats per packed gaussian (112 B = 7 x 16 B)
#define NCELL   4096       // 16^3 morton cells

#define SH_C0 0.28209479177387814f
#define SH_C1 0.4886025119029199f

// Workspace (floats): gp [0, 114688) ; perm (int) [114688, 147456)  => 576 KB
#define WS_GP   0
#define WS_PERM (N_GAUSS * GSTRIDE)

// ---------------------------------------------------------------------------
// Fused pre-kernel, 21 blocks x 1024 threads:
//   block 0      : full counting sort of points into morton cells (LDS-resident)
//   blocks 1..4  : per-gaussian preprocessing (pack gp)
//   blocks 5..20 : zero d_out (float4 stores)
// Gaussian record (28 floats):
//   [0..2] center  [3] cull threshold Tg (skip if d2min > Tg)
//   [4..9] 0.5*precision (maha' = d^T P' d)  [10] ln(opacity)  [11] pad
//   [12..27] SH coeffs, constants pre-multiplied
// ---------------------------------------------------------------------------
__device__ __forceinline__ int expand4(int b) {
    return (b & 1) | ((b & 2) << 2) | ((b & 4) << 4) | ((b & 8) << 6);
}

__global__ __launch_bounds__(1024) void pre_kernel(
    const float* __restrict__ pts, const float* __restrict__ xyz,
    const float* __restrict__ sh_dc, const float* __restrict__ sh_rest,
    const float* __restrict__ scaling, const float* __restrict__ rotation,
    const float* __restrict__ opl, float* __restrict__ gp,
    int* __restrict__ perm, float* __restrict__ out)
{
    __shared__ unsigned short s_cell[N_PTS];   // 64 KB
    __shared__ int s_hist[NCELL];              // 16 KB
    __shared__ int s_scan[1024];               // 4 KB

    const int t  = threadIdx.x;
    const int bx = blockIdx.x;

    if (bx == 0) {
        // ---- counting sort (single block) ----
        for (int c = t; c < NCELL; c += 1024) s_hist[c] = 0;
        __syncthreads();
        for (int p = t; p < N_PTS; p += 1024) {
            float x = pts[3*p+0], y = pts[3*p+1], z = pts[3*p+2];
            int cx = min(15, max(0, (int)((x + 3.2f) * 2.5f)));
            int cy = min(15, max(0, (int)((y + 3.2f) * 2.5f)));
            int cz = min(15, max(0, (int)((z + 3.2f) * 2.5f)));
            int cell = expand4(cx) | (expand4(cy) << 1) | (expand4(cz) << 2);
            s_cell[p] = (unsigned short)cell;
            atomicAdd(&s_hist[cell], 1);
        }
        __syncthreads();
        // exclusive scan over 4096 counts (1024 threads x 4)
        int b = t * 4;
        int c0 = s_hist[b], c1 = s_hist[b+1], c2 = s_hist[b+2], c3 = s_hist[b+3];
        int s = c0 + c1 + c2 + c3;
        s_scan[t] = s;
        __syncthreads();
        for (int off = 1; off < 1024; off <<= 1) {
            int v = (t >= off) ? s_scan[t - off] : 0;
            __syncthreads();
            s_scan[t] += v;
            __syncthreads();
        }
        int excl = s_scan[t] - s;
        s_hist[b] = excl; s_hist[b+1] = excl + c0;
        s_hist[b+2] = excl + c0 + c1; s_hist[b+3] = excl + c0 + c1 + c2;
        __syncthreads();
        for (int p = t; p < N_PTS; p += 1024) {
            int pos = atomicAdd(&s_hist[s_cell[p]], 1);
            perm[pos] = p;
        }
    } else if (bx <= 4) {
        // ---- gaussian prep ----
        int g = (bx - 1) * 1024 + t;

        float s0 = scaling[3*g+0], s1 = scaling[3*g+1], s2 = scaling[3*g+2];
        float i0 = __expf(-2.0f * s0);
        float i1 = __expf(-2.0f * s1);
        float i2 = __expf(-2.0f * s2);
        float maxs2 = __expf(2.0f * fmaxf(s0, fmaxf(s1, s2)));

        float r = rotation[4*g+0], x = rotation[4*g+1];
        float y = rotation[4*g+2], z = rotation[4*g+3];
        float n = rsqrtf(r*r + x*x + y*y + z*z);
        r *= n; x *= n; y *= n; z *= n;
        float R00 = 1.f - 2.f*(y*y + z*z), R01 = 2.f*(x*y - r*z), R02 = 2.f*(x*z + r*y);
        float R10 = 2.f*(x*y + r*z), R11 = 1.f - 2.f*(x*x + z*z), R12 = 2.f*(y*z - r*x);
        float R20 = 2.f*(x*z - r*y), R21 = 2.f*(y*z + r*x), R22 = 1.f - 2.f*(x*x + y*y);

        float pxx = 0.5f*(R00*R00*i0 + R01*R01*i1 + R02*R02*i2);
        float pxy = 0.5f*(R00*R10*i0 + R01*R11*i1 + R02*R12*i2);
        float pxz = 0.5f*(R00*R20*i0 + R01*R21*i1 + R02*R22*i2);
        float pyy = 0.5f*(R10*R10*i0 + R11*R11*i1 + R12*R12*i2);
        float pyz = 0.5f*(R10*R20*i0 + R11*R21*i1 + R12*R22*i2);
        float pzz = 0.5f*(R20*R20*i0 + R21*R21*i1 + R22*R22*i2);

        float op   = 1.f / (1.f + __expf(-opl[g]));
        float lnop = __logf(op);
        float Tg   = 2.0f * maxs2 * (lnop + 30.0f);   // d2 > Tg => w < 1e-13

        float* G = gp + (size_t)g * GSTRIDE;
        G[0] = xyz[3*g+0]; G[1] = xyz[3*g+1]; G[2] = xyz[3*g+2]; G[3] = Tg;
        G[4] = pxx; G[5] = pxy; G[6] = pxz; G[7] = pyy; G[8] = pyz; G[9] = pzz;
        G[10] = lnop; G[11] = 0.f;

        const float* sr = sh_rest + (size_t)g * 15;
        G[12] =  SH_C0 * sh_dc[g];
        G[13] = -SH_C1 * sr[0];
        G[14] =  SH_C1 * sr[1];
        G[15] = -SH_C1 * sr[2];
        G[16] =  1.0925484305920792f  * sr[3];
        G[17] = -1.0925484305920792f  * sr[4];
        G[18] =  0.31539156525252005f * sr[5];
        G[19] = -1.0925484305920792f  * sr[6];
        G[20] =  0.5462742152960396f  * sr[7];
        G[21] = -0.5900435899266435f  * sr[8];
        G[22] =  2.890611442640554f   * sr[9];
        G[23] = -0.4570457994644658f  * sr[10];
        G[24] =  0.3731763325901154f  * sr[11];
        G[25] = -0.4570457994644658f  * sr[12];
        G[26] =  1.445305721320277f   * sr[13];
        G[27] = -0.5900435899266435f  * sr[14];
    } else {
        // ---- zero d_out: 16 blocks x 1024 threads x float4 = 65536 floats ----
        int idx = (bx - 5) * 1024 + t;
        ((float4*)out)[idx] = make_float4(0.f, 0.f, 0.f, 0.f);
    }
}

// ---------------------------------------------------------------------------
// Main kernel. Per block: AABB over its 256 sorted points -> conservative
// per-gaussian cull (1 thread = 1 gaussian) -> LDS-compacted active list ->
// dense eval loop with scalar gaussian loads.
// ---------------------------------------------------------------------------
__global__ __launch_bounds__(BLOCK) void gauss_kernel(
    const float* __restrict__ pts, const float* __restrict__ gp,
    const int* __restrict__ perm, float* __restrict__ out)
{
    __shared__ float s_min[4][3], s_max[4][3];
    __shared__ int s_nact;
    __shared__ int s_act[BLOCK];

    const int tid = threadIdx.x;
    const int gid = blockIdx.x * BLOCK + tid;
    const int pt  = perm[gid];
    const float px = pts[3*pt+0], py = pts[3*pt+1], pz = pts[3*pt+2];

    // wave-level min/max, then block AABB via LDS
    float mnx = px, mxx = px, mny = py, mxy = py, mnz = pz, mxz = pz;
    #pragma unroll
    for (int off = 32; off >= 1; off >>= 1) {
        mnx = fminf(mnx, __shfl_xor(mnx, off));
        mxx = fmaxf(mxx, __shfl_xor(mxx, off));
        mny = fminf(mny, __shfl_xor(mny, off));
        mxy = fmaxf(mxy, __shfl_xor(mxy, off));
        mnz = fminf(mnz, __shfl_xor(mnz, off));
        mxz = fmaxf(mxz, __shfl_xor(mxz, off));
    }
    const int wave = tid >> 6;
    if ((tid & 63) == 0) {
        s_min[wave][0] = mnx; s_min[wave][1] = mny; s_min[wave][2] = mnz;
        s_max[wave][0] = mxx; s_max[wave][1] = mxy; s_max[wave][2] = mxz;
    }
    if (tid == 0) s_nact = 0;
    __syncthreads();
    const float bmnx = fminf(fminf(s_min[0][0], s_min[1][0]), fminf(s_min[2][0], s_min[3][0]));
    const float bmny = fminf(fminf(s_min[0][1], s_min[1][1]), fminf(s_min[2][1], s_min[3][1]));
    const float bmnz = fminf(fminf(s_min[0][2], s_min[1][2]), fminf(s_min[2][2], s_min[3][2]));
    const float bmxx = fmaxf(fmaxf(s_max[0][0], s_max[1][0]), fmaxf(s_max[2][0], s_max[3][0]));
    const float bmxy = fmaxf(fmaxf(s_max[0][1], s_max[1][1]), fmaxf(s_max[2][1], s_max[3][1]));
    const float bmxz = fmaxf(fmaxf(s_max[0][2], s_max[1][2]), fmaxf(s_max[2][2], s_max[3][2]));

    // conservative cull: min distance from AABB to center vs Tg
    {
        const int gg = blockIdx.y * (N_GAUSS / NSPLIT) + tid;
        float4 cg = *(const float4*)(gp + (size_t)gg * GSTRIDE);
        float ddx = fmaxf(0.f, fmaxf(bmnx - cg.x, cg.x - bmxx));
        float ddy = fmaxf(0.f, fmaxf(bmny - cg.y, cg.y - bmxy));
        float ddz = fmaxf(0.f, fmaxf(bmnz - cg.z, cg.z - bmxz));
        float dd2 = ddx*ddx + ddy*ddy + ddz*ddz;
        if (dd2 <= cg.w) {                 // some point in block may have w >= 1e-13
            int slot = atomicAdd(&s_nact, 1);
            s_act[slot] = gg;
        }
    }
    __syncthreads();
    const int nact = s_nact;

    float opac = 0.f, sig = 0.f;
    for (int j = 0; j < nact; ++j) {
        const int g = __builtin_amdgcn_readfirstlane(s_act[j]);
        const float* __restrict__ G = gp + (size_t)g * GSTRIDE;
        float dx = px - G[0], dy = py - G[1], dz = pz - G[2];

        float vx = G[4]*dx + G[5]*dy + G[6]*dz;
        float vy = G[5]*dx + G[7]*dy + G[8]*dz;
        float vz = G[6]*dx + G[8]*dy + G[9]*dz;
        float maha = dx*vx + dy*vy + dz*vz;       // includes the 0.5
        float w = __expf(G[10] - maha);           // op * exp(-0.5*maha)
        opac += w;

        if (__any(w > 1e-13f)) {
            float d2   = dx*dx + dy*dy + dz*dz;
            float rinv = rsqrtf(d2);
            float x = -dx * rinv, y = -dy * rinv, z = -dz * rinv;
            float xx = x*x, yy = y*y, zz = z*z;
            float xy = x*y, yz = y*z, xz = x*z;

            float res = G[12];
            res += y * G[13];
            res += z * G[14];
            res += x * G[15];
            res += xy * G[16];
            res += yz * G[17];
            res += (3.f*zz - 1.f) * G[18];
            res += xz * G[19];
            float xxmyy = xx - yy;
            res += xxmyy * G[20];
            res += y * (3.f*xx - yy) * G[21];
            res += (xy * z) * G[22];
            float f5z1 = 5.f*zz - 1.f;
            res += y * f5z1 * G[23];
            res += z * (5.f*zz - 3.f) * G[24];
            res += x * f5z1 * G[25];
            res += z * xxmyy * G[26];
            res += x * (xxmyy - 3.f*zz) * G[27];

            sig += w * fmaxf(res, 0.f);
        }
    }

    atomicAdd(&out[pt], opac);
    atomicAdd(&out[N_PTS + pt], sig);
}

extern "C" void kernel_launch(void* const* d_in, const int* in_sizes, int n_in,
                              void* d_out, int out_size, void* d_ws, size_t ws_size,
                              hipStream_t stream) {
    const float* pts      = (const float*)d_in[0];
    const float* xyz      = (const float*)d_in[3];
    const float* sh_dc    = (const float*)d_in[4];
    const float* sh_rest  = (const float*)d_in[5];
    const float* scaling  = (const float*)d_in[6];
    const float* rotation = (const float*)d_in[7];
    const float* opl      = (const float*)d_in[8];

    float* out  = (float*)d_out;
    float* wsf  = (float*)d_ws;
    float* gp   = wsf + WS_GP;
    int*   perm = (int*)(wsf + WS_PERM);

    pre_kernel<<<dim3(21), dim3(1024), 0, stream>>>(
        pts, xyz, sh_dc, sh_rest, scaling, rotation, opl, gp, perm, out);

    dim3 grid(N_PTS / BLOCK, NSPLIT);
    gauss_kernel<<<grid, dim3(BLOCK), 0, stream>>>(pts, gp, perm, out);
}